// Round 1
// baseline (85.531 us; speedup 1.0000x reference)
//
#include <hip/hip_runtime.h>

namespace {
constexpr int NA  = 128;
constexpr int NC2 = NA * (NA - 1) / 2;           // 8128
constexpr float SCALE = 627.5095f * 0.529177f / 100.0f;  // AU2KCALMOLA / MAX_NRF
}

// One block per batch row. Coords staged to LDS as padded float4 so each
// atom access is a single conflict-free ds_read_b128. Each thread produces
// 4 consecutive pairs -> one float4 coalesced store. (i,j) derived from the
// linear strict-lower-triangle pair index p: i = floor((1+sqrt(8p+1))/2)
// with integer fixup for fp32 sqrt rounding, then incremental advance.
__global__ __launch_bounds__(256) void nrf_kernel(
    const float* __restrict__ coords,
    const float* __restrict__ atoms,
    float* __restrict__ out)
{
    __shared__ float4 c4[NA + 2];   // +2: harmless overread when the last
                                    // chunk advances past row 127
    const int b   = blockIdx.x;
    const int tid = threadIdx.x;

    // Stage coords[b] (384 contiguous floats) -> padded SoA-ish float4 LDS.
    const float* cb = coords + (size_t)b * (NA * 3);
    for (int k = tid; k < NA * 3; k += 256) {
        int atom = k / 3;            // magic-mul, compile-time constant div
        int comp = k - atom * 3;
        reinterpret_cast<float*>(&c4[atom])[comp] = cb[k];
    }
    __syncthreads();

    float4*       outb = reinterpret_cast<float4*>(out + (size_t)b * NC2);
    const float4* a4   = reinterpret_cast<const float4*>(atoms);

    for (int q = tid; q < NC2 / 4; q += 256) {
        int p = q * 4;
        // row index from inverse triangular number, with rounding fixup
        int i = (int)((1.0f + sqrtf((float)(8 * p + 1))) * 0.5f);
        while (i * (i - 1) / 2 > p) --i;
        while ((i + 1) * i / 2 <= p) ++i;
        int j = p - i * (i - 1) / 2;

        float4 av = a4[q];
        float  am[4] = {av.x, av.y, av.z, av.w};
        float  res[4];
        float4 ci = c4[i];
        #pragma unroll
        for (int k = 0; k < 4; ++k) {
            float4 cj = c4[j];
            float dx = ci.x - cj.x;
            float dy = ci.y - cj.y;
            float dz = ci.z - cj.z;
            float d2 = dx * dx + dy * dy + dz * dz;
            // ref: 1/(sqrt(d2))^2 == 1/d2 within ~2 ulp; v_rcp_f32 is 1 ulp.
            res[k] = am[k] * SCALE * __builtin_amdgcn_rcpf(d2);
            if (++j == i) { ++i; j = 0; ci = c4[i]; }  // next row
        }
        outb[q] = make_float4(res[0], res[1], res[2], res[3]);
    }
}

extern "C" void kernel_launch(void* const* d_in, const int* in_sizes, int n_in,
                              void* d_out, int out_size, void* d_ws, size_t ws_size,
                              hipStream_t stream)
{
    const float* coords = (const float*)d_in[0];
    const float* atoms  = (const float*)d_in[1];
    float*       out    = (float*)d_out;
    const int batch = in_sizes[0] / (NA * 3);    // 2048
    nrf_kernel<<<batch, 256, 0, stream>>>(coords, atoms, out);
}